// Round 5
// baseline (780.572 us; speedup 1.0000x reference)
//
#include <hip/hip_runtime.h>

#define CIN   64
#define COUT  128
#define HIN   128
#define WIN   128
#define HOUT  126
#define WOUT  126
#define HP    63
#define WP    63
#define NB    32
#define NG    16
#define EPS   1e-5f
#define KTOT  576            // 9 * 64, k = (kh*3+kw)*64 + ci

// LDS x-tile: [6 rows][66 cols][cell = 32 ci bf16 (64B) + 16B pad = 80B]
#define CELLB 80
#define NCOLT 66
#define ROWB  (NCOLT * CELLB)   // 5280
#define XBYTES (6 * ROWB)       // 31680 per array (hi, lo)
#define NTILE 64                // rt*2 + ct

// tiled y: [b][co][pair(63)][ct(2)][row(2)][col(64)] ; chunk = 128 floats (512B)
// chunk id = (oh>>1)*2 + ct ; within: (oh&1)*64 + colInTile
#define YCHUNK 128
#define YPLANE (126 * YCHUNK)   // 16128 floats per (b,co)

typedef __attribute__((ext_vector_type(8))) short short8;
typedef __attribute__((ext_vector_type(4))) float f32x4;

static __device__ __forceinline__ ushort f2bf(float v) {
    unsigned int u = __float_as_uint(v);
    return (ushort)((u + 0x7fffu + ((u >> 16) & 1u)) >> 16);   // RN-even
}
static __device__ __forceinline__ float bf2f(ushort h) {
    return __uint_as_float(((unsigned int)h) << 16);
}

// ---- weight prep: cw[co][ci][3][3] f32 -> wt[co][k] bf16 hi/lo, k=(kh*3+kw)*64+ci
__global__ __launch_bounds__(256) void wprep_kernel(
    const float* __restrict__ cw, ushort* __restrict__ wh, ushort* __restrict__ wl)
{
    int idx = blockIdx.x * 256 + threadIdx.x;
    if (idx >= COUT * KTOT) return;
    int co = idx / KTOT, k = idx - co * KTOT;
    int khw = k >> 6, ci = k & 63;
    float v = cw[(co * CIN + ci) * 9 + khw];
    ushort h = f2bf(v);
    wh[idx] = h;
    wl[idx] = f2bf(v - bf2f(h));
}

// ---- conv implicit GEMM: block = 4 out rows x 64 cols x 128 couts
__global__ __launch_bounds__(512, 4) void conv_mfma_kernel(
    const float* __restrict__ x, const ushort* __restrict__ wt_hi,
    const ushort* __restrict__ wt_lo, const float* __restrict__ cb,
    float* __restrict__ y, float* __restrict__ partials)
{
    __shared__ char xs_hi[XBYTES];
    __shared__ char xs_lo[XBYTES];
    __shared__ float wred[8][4][2][2];

    const int tid = threadIdx.x;
    // XCD swizzle: each XCD gets 4 whole images, consecutive (rt,ct) tiles
    const int bid = blockIdx.x;
    const int w   = (bid & 7) * 256 + (bid >> 3);
    const int ct  = w & 1;
    const int rt  = (w >> 1) & 31;
    const int b   = w >> 6;
    const int r0  = rt * 4;

    const int l = tid & 63, wid = tid >> 6;
    const int wm = wid >> 2, wr = wid & 3;       // wm: cout half, wr: row
    const int l15 = l & 15, lhi = l >> 4;

    f32x4 acc[4][4];
#pragma unroll
    for (int mt = 0; mt < 4; ++mt)
#pragma unroll
        for (int nt = 0; nt < 4; ++nt)
            acc[mt][nt] = (f32x4){0.f, 0.f, 0.f, 0.f};

    const float* xb = x + (size_t)b * (CIN * HIN * WIN);
    const char* pbh = xs_hi + wr * ROWB + l15 * CELLB + lhi * 16;
    const char* pbl = xs_lo + wr * ROWB + l15 * CELLB + lhi * 16;

    for (int cip = 0; cip < 2; ++cip) {
        if (cip) __syncthreads();                // prev compute done
        // ---- stage 32-ci chunk: tasks = cig(8) x r(6) x c4(17) = 816
        for (int t = 0; t < 2; ++t) {
            int gid = t * 512 + tid;
            if (gid < 816) {
                int c4  = gid % 17;
                int rr  = (gid / 17) % 6;
                int cig = gid / 102;
                int row = r0 + rr;
                bool rowok = row < HIN;
                bool colok = (ct == 0) | (c4 < 16);   // avoid OOB float4 at gcol=128
                f32x4 f[4];
                const float* xp = xb + (size_t)(cip * 32 + cig * 4) * (HIN * WIN)
                                + row * WIN + ct * 64 + c4 * 4;
#pragma unroll
                for (int q = 0; q < 4; ++q) {
                    if (rowok && colok)
                        f[q] = *(const f32x4*)(xp + q * (HIN * WIN));
                    else
                        f[q] = (f32x4){0.f, 0.f, 0.f, 0.f};
                }
#pragma unroll
                for (int j = 0; j < 4; ++j) {
                    int lc = c4 * 4 + j;
                    if (lc < NCOLT) {
                        ushort h0 = f2bf(f[0][j]), h1 = f2bf(f[1][j]);
                        ushort h2 = f2bf(f[2][j]), h3 = f2bf(f[3][j]);
                        ushort g0 = f2bf(f[0][j] - bf2f(h0));
                        ushort g1 = f2bf(f[1][j] - bf2f(h1));
                        ushort g2 = f2bf(f[2][j] - bf2f(h2));
                        ushort g3 = f2bf(f[3][j] - bf2f(h3));
                        uint2 hp, lp;
                        hp.x = (unsigned)h0 | ((unsigned)h1 << 16);
                        hp.y = (unsigned)h2 | ((unsigned)h3 << 16);
                        lp.x = (unsigned)g0 | ((unsigned)g1 << 16);
                        lp.y = (unsigned)g2 | ((unsigned)g3 << 16);
                        int off = (rr * NCOLT + lc) * CELLB + cig * 8;
                        *(uint2*)(xs_hi + off) = hp;
                        *(uint2*)(xs_lo + off) = lp;
                    }
                }
            }
        }
        __syncthreads();

        // ---- compute this ci-chunk
        const ushort* wbh = wt_hi + (size_t)(wm * 64 + l15) * KTOT + cip * 32 + lhi * 8;
        const ushort* wbl = wt_lo + (size_t)(wm * 64 + l15) * KTOT + cip * 32 + lhi * 8;
#pragma unroll
        for (int kh = 0; kh < 3; ++kh) {
#pragma unroll
            for (int kw = 0; kw < 3; ++kw) {
                short8 bh[4], bl[4];
#pragma unroll
                for (int nt = 0; nt < 4; ++nt) {
                    bh[nt] = *(const short8*)(pbh + kh * ROWB + (nt * 16 + kw) * CELLB);
                    bl[nt] = *(const short8*)(pbl + kh * ROWB + (nt * 16 + kw) * CELLB);
                }
#pragma unroll
                for (int mt = 0; mt < 4; ++mt) {
                    short8 ah = *(const short8*)(wbh + mt * 16 * KTOT + (kh * 3 + kw) * 64);
                    short8 al = *(const short8*)(wbl + mt * 16 * KTOT + (kh * 3 + kw) * 64);
#pragma unroll
                    for (int nt = 0; nt < 4; ++nt) {
                        acc[mt][nt] = __builtin_amdgcn_mfma_f32_16x16x32_bf16(
                            ah, bh[nt], acc[mt][nt], 0, 0, 0);
                        acc[mt][nt] = __builtin_amdgcn_mfma_f32_16x16x32_bf16(
                            al, bh[nt], acc[mt][nt], 0, 0, 0);
                        acc[mt][nt] = __builtin_amdgcn_mfma_f32_16x16x32_bf16(
                            ah, bl[nt], acc[mt][nt], 0, 0, 0);
                    }
                }
            }
        }
    }

    // ---- epilogue: bias, store y (2x64 chunks, predicated on valid row), partials
    const int oh = r0 + wr;
    const bool rowok = oh < HOUT;
    float cbv[4][4];
#pragma unroll
    for (int mt = 0; mt < 4; ++mt)
#pragma unroll
        for (int r = 0; r < 4; ++r)
            cbv[mt][r] = cb[wm * 64 + mt * 16 + lhi * 4 + r];

    // base for (b, co=0): chunk = (oh>>1)*2 + ct, within-chunk (oh&1)*64 + l15
    float* ybase = y + (size_t)b * COUT * YPLANE
                 + (size_t)(((oh >> 1) * 2 + ct) * YCHUNK) + (oh & 1) * 64 + l15;

#pragma unroll
    for (int mt = 0; mt < 4; ++mt) {
        float s1 = 0.f, s2 = 0.f;
#pragma unroll
        for (int r = 0; r < 4; ++r) {
            int co = wm * 64 + mt * 16 + lhi * 4 + r;
            float* yp = ybase + (size_t)co * YPLANE;
#pragma unroll
            for (int nt = 0; nt < 4; ++nt) {
                float v = acc[mt][nt][r] + cbv[mt][r];
                if (rowok) yp[nt * 16] = v;
                bool ok = rowok && (ct * 64 + nt * 16 + l15 < WOUT);
                if (ok) { s1 += v; s2 += v * v; }
            }
        }
#pragma unroll
        for (int d = 1; d < 32; d <<= 1) {
            s1 += __shfl_xor(s1, d);
            s2 += __shfl_xor(s2, d);
        }
        if ((l & 31) == 0) {
            wred[wid][mt][l >> 5][0] = s1;
            wred[wid][mt][l >> 5][1] = s2;
        }
    }
    __syncthreads();

    if (tid < NG) {
        int g = tid;
        int gwm = g >> 3, mt = (g >> 1) & 3, half = g & 1;
        float t1 = 0.f, t2 = 0.f;
#pragma unroll
        for (int wrv = 0; wrv < 4; ++wrv) {
            t1 += wred[gwm * 4 + wrv][mt][half][0];
            t2 += wred[gwm * 4 + wrv][mt][half][1];
        }
        size_t pidx = (((size_t)b * NG + g) * NTILE + (rt * 2 + ct)) * 2;
        partials[pidx + 0] = t1;
        partials[pidx + 1] = t2;
    }
}

__global__ void stats_kernel(const float* __restrict__ partials,
                             float* __restrict__ stats)
{
    int t = blockIdx.x * blockDim.x + threadIdx.x;
    if (t >= NB * NG) return;
    float s1 = 0.f, s2 = 0.f;
    for (int j = 0; j < NTILE; ++j) {
        s1 += partials[((size_t)t * NTILE + j) * 2 + 0];
        s2 += partials[((size_t)t * NTILE + j) * 2 + 1];
    }
    const float N = 8.f * HOUT * WOUT;
    float mean = s1 / N;
    float var = s2 / N - mean * mean;
    stats[t * 2 + 0] = mean;
    stats[t * 2 + 1] = rsqrtf(var + EPS);
}

__global__ __launch_bounds__(256) void pool_kernel(
    const float* __restrict__ y, const float* __restrict__ stats,
    const float* __restrict__ gw, const float* __restrict__ gb,
    const float* __restrict__ sc, float* __restrict__ out)
{
    int idx = blockIdx.x * 256 + threadIdx.x;
    if (idx >= NB * COUT * HP * WP) return;
    int owp = idx % WP;
    int t = idx / WP;
    int ohp = t % HP; t /= HP;
    int c = t % COUT;
    int b = t / COUT;
    int g = c >> 3;

    float mean = stats[(b * NG + g) * 2 + 0];
    float rstd = stats[(b * NG + g) * 2 + 1];
    float ga = rstd * gw[c] * sc[c];
    float gbb = (gb[c] - mean * rstd * gw[c]) * sc[c];

    // tiled y: chunk = ohp*2 + (owp>>5); rows (0,1) of chunk; col = (2*owp)&63
    int ct = owp >> 5, col = (2 * owp) & 63;
    const float* yp = y + (size_t)(b * COUT + c) * YPLANE
                    + (ohp * 2 + ct) * YCHUNK + col;
    float2 r0 = *reinterpret_cast<const float2*>(yp);
    float2 r1 = *reinterpret_cast<const float2*>(yp + 64);
    float v0 = fmaf(r0.x, ga, gbb);
    float v1 = fmaf(r0.y, ga, gbb);
    float v2 = fmaf(r1.x, ga, gbb);
    float v3 = fmaf(r1.y, ga, gbb);
    float m = fmaxf(fmaxf(v0, v1), fmaxf(v2, v3));
    out[idx] = fminf(fmaxf(m, 0.f), 1.f);
}

extern "C" void kernel_launch(void* const* d_in, const int* in_sizes, int n_in,
                              void* d_out, int out_size, void* d_ws, size_t ws_size,
                              hipStream_t stream)
{
    const float* x  = (const float*)d_in[0];
    const float* cw = (const float*)d_in[1];
    const float* cbias = (const float*)d_in[2];
    const float* gw = (const float*)d_in[3];
    const float* gb = (const float*)d_in[4];
    const float* sc = (const float*)d_in[5];
    float* out = (float*)d_out;

    // ws budget: y 264,241,152 B + partials 262,144 + stats 4,096 + weights
    // 294,912 = 264,802,304 B = 252.5 MiB  (fits 256 MiB; round-4's 269 MB overflowed)
    const size_t YSZ = (size_t)NB * COUT * YPLANE;               // 66,060,288 f32
    float* y        = (float*)d_ws;
    float* partials = y + YSZ;                                   // 32*16*64*2 f32
    float* stats    = partials + (size_t)NB * NG * NTILE * 2;    // 1024 f32
    ushort* wh      = (ushort*)(stats + 1024);                   // 128*576 bf16
    ushort* wl      = wh + (size_t)COUT * KTOT;

    hipLaunchKernelGGL(wprep_kernel, dim3((COUT * KTOT + 255) / 256), dim3(256),
                       0, stream, cw, wh, wl);

    hipLaunchKernelGGL(conv_mfma_kernel, dim3(2048), dim3(512), 0, stream,
                       x, wh, wl, cbias, y, partials);

    hipLaunchKernelGGL(stats_kernel, dim3(2), dim3(256), 0, stream,
                       partials, stats);

    int total = NB * COUT * HP * WP;
    hipLaunchKernelGGL(pool_kernel, dim3((total + 255) / 256), dim3(256), 0, stream,
                       y, stats, gw, gb, sc, out);
}

// Round 6
// 514.578 us; speedup vs baseline: 1.5169x; 1.5169x over previous
//
#include <hip/hip_runtime.h>

#define CIN   64
#define COUT  128
#define HIN   128
#define WIN   128
#define HOUT  126
#define WOUT  126
#define HP    63
#define WP    63
#define NB    32
#define NG    16
#define EPS   1e-5f
#define KTOT  576            // 9 * 64, k = (kh*3+kw)*64 + ci

// LDS x-tile: [4 rows][66 cols][cell = 32 ci bf16 (64B) + 16B pad = 80B]
#define CELLB 80
#define NCOLT 66
#define ROWB  (NCOLT * CELLB)   // 5280
#define XBYTES (4 * ROWB)       // 21120 per array (hi, lo)
#define NTILE 126               // rp*2 + ct

// tiled y: [b][co][chunk(126)][row(2)][col(64)] ; chunk = 128 floats (512B)
// chunk id = (oh>>1)*2 + ct ; within: (oh&1)*64 + colInTile
#define YCHUNK 128
#define YPLANE (126 * YCHUNK)   // 16128 floats per (b,co)

typedef __attribute__((ext_vector_type(8))) short short8;
typedef __attribute__((ext_vector_type(4))) float f32x4;

static __device__ __forceinline__ ushort f2bf(float v) {
    unsigned int u = __float_as_uint(v);
    return (ushort)((u + 0x7fffu + ((u >> 16) & 1u)) >> 16);   // RN-even
}
static __device__ __forceinline__ float bf2f(ushort h) {
    return __uint_as_float(((unsigned int)h) << 16);
}

// ---- weight prep: cw[co][ci][3][3] f32 -> wt[co][k] bf16 hi/lo, k=(kh*3+kw)*64+ci
__global__ __launch_bounds__(256) void wprep_kernel(
    const float* __restrict__ cw, ushort* __restrict__ wh, ushort* __restrict__ wl)
{
    int idx = blockIdx.x * 256 + threadIdx.x;
    if (idx >= COUT * KTOT) return;
    int co = idx / KTOT, k = idx - co * KTOT;
    int khw = k >> 6, ci = k & 63;
    float v = cw[(co * CIN + ci) * 9 + khw];
    ushort h = f2bf(v);
    wh[idx] = h;
    wl[idx] = f2bf(v - bf2f(h));
}

// ---- conv implicit GEMM: block = 2 out rows x 64 cols x 128 couts, 4 waves
__global__ __launch_bounds__(256, 3) void conv_mfma_kernel(
    const float* __restrict__ x, const ushort* __restrict__ wt_hi,
    const ushort* __restrict__ wt_lo, const float* __restrict__ cb,
    float* __restrict__ y, float* __restrict__ partials)
{
    __shared__ char xs_hi[XBYTES];
    __shared__ char xs_lo[XBYTES];
    __shared__ float wred[4][4][2][2];

    const int tid = threadIdx.x;
    // XCD swizzle: 4032 blocks = 8 XCDs x 504; each XCD gets 4 whole images
    const int bid = blockIdx.x;
    const int w   = (bid & 7) * 504 + (bid >> 3);
    const int b   = w / 126;
    const int r   = w - b * 126;
    const int rp  = r >> 1;            // 0..62 row pair
    const int ct  = r & 1;             // col tile
    const int r0x = rp * 2;            // first x row needed

    const int l = tid & 63, wid = tid >> 6;
    const int wr = wid >> 1, wm = wid & 1;       // wr: row, wm: cout half
    const int l15 = l & 15, lhi = l >> 4;

    f32x4 acc[4][4];
#pragma unroll
    for (int mt = 0; mt < 4; ++mt)
#pragma unroll
        for (int nt = 0; nt < 4; ++nt)
            acc[mt][nt] = (f32x4){0.f, 0.f, 0.f, 0.f};

    const float* xb = x + (size_t)b * (CIN * HIN * WIN);
    const char* pbh = xs_hi + wr * ROWB + l15 * CELLB + lhi * 16;
    const char* pbl = xs_lo + wr * ROWB + l15 * CELLB + lhi * 16;

    for (int cip = 0; cip < 2; ++cip) {
        if (cip) __syncthreads();                // prev compute done
        // ---- stage 32-ci chunk: tasks = cig(8) x row(4) x c4(17) = 544
        for (int t = 0; t < 3; ++t) {
            int gid = t * 256 + tid;
            if (gid < 544) {
                int c4  = gid % 17;
                int rr  = (gid / 17) & 3;
                int cig = gid / 68;
                int row = r0x + rr;               // always < HIN (rp<=62 -> row<=127)
                bool colok = (ct == 0) | (c4 < 16);   // avoid OOB float4 at gcol=128
                f32x4 f[4];
                const float* xp = xb + (size_t)(cip * 32 + cig * 4) * (HIN * WIN)
                                + row * WIN + ct * 64 + c4 * 4;
#pragma unroll
                for (int q = 0; q < 4; ++q) {
                    if (colok)
                        f[q] = *(const f32x4*)(xp + q * (HIN * WIN));
                    else
                        f[q] = (f32x4){0.f, 0.f, 0.f, 0.f};
                }
#pragma unroll
                for (int j = 0; j < 4; ++j) {
                    int lc = c4 * 4 + j;
                    if (lc < NCOLT) {
                        ushort h0 = f2bf(f[0][j]), h1 = f2bf(f[1][j]);
                        ushort h2 = f2bf(f[2][j]), h3 = f2bf(f[3][j]);
                        ushort g0 = f2bf(f[0][j] - bf2f(h0));
                        ushort g1 = f2bf(f[1][j] - bf2f(h1));
                        ushort g2 = f2bf(f[2][j] - bf2f(h2));
                        ushort g3 = f2bf(f[3][j] - bf2f(h3));
                        uint2 hp, lp;
                        hp.x = (unsigned)h0 | ((unsigned)h1 << 16);
                        hp.y = (unsigned)h2 | ((unsigned)h3 << 16);
                        lp.x = (unsigned)g0 | ((unsigned)g1 << 16);
                        lp.y = (unsigned)g2 | ((unsigned)g3 << 16);
                        int off = (rr * NCOLT + lc) * CELLB + cig * 8;
                        *(uint2*)(xs_hi + off) = hp;
                        *(uint2*)(xs_lo + off) = lp;
                    }
                }
            }
        }
        __syncthreads();

        // ---- compute this ci-chunk
        const ushort* wbh = wt_hi + (size_t)(wm * 64 + l15) * KTOT + cip * 32 + lhi * 8;
        const ushort* wbl = wt_lo + (size_t)(wm * 64 + l15) * KTOT + cip * 32 + lhi * 8;
#pragma unroll
        for (int kh = 0; kh < 3; ++kh) {
#pragma unroll
            for (int kw = 0; kw < 3; ++kw) {
                short8 bh[4], bl[4];
#pragma unroll
                for (int nt = 0; nt < 4; ++nt) {
                    bh[nt] = *(const short8*)(pbh + kh * ROWB + (nt * 16 + kw) * CELLB);
                    bl[nt] = *(const short8*)(pbl + kh * ROWB + (nt * 16 + kw) * CELLB);
                }
#pragma unroll
                for (int mt = 0; mt < 4; ++mt) {
                    short8 ah = *(const short8*)(wbh + mt * 16 * KTOT + (kh * 3 + kw) * 64);
                    short8 al = *(const short8*)(wbl + mt * 16 * KTOT + (kh * 3 + kw) * 64);
#pragma unroll
                    for (int nt = 0; nt < 4; ++nt) {
                        acc[mt][nt] = __builtin_amdgcn_mfma_f32_16x16x32_bf16(
                            ah, bh[nt], acc[mt][nt], 0, 0, 0);
                        acc[mt][nt] = __builtin_amdgcn_mfma_f32_16x16x32_bf16(
                            al, bh[nt], acc[mt][nt], 0, 0, 0);
                        acc[mt][nt] = __builtin_amdgcn_mfma_f32_16x16x32_bf16(
                            ah, bl[nt], acc[mt][nt], 0, 0, 0);
                    }
                }
            }
        }
    }

    // ---- epilogue: bias, store y (all rows valid), group partials
    const int oh = r0x + wr;
    float cbv[4][4];
#pragma unroll
    for (int mt = 0; mt < 4; ++mt)
#pragma unroll
        for (int r2 = 0; r2 < 4; ++r2)
            cbv[mt][r2] = cb[wm * 64 + mt * 16 + lhi * 4 + r2];

    // base for (b, co=0): chunk = rp*2 + ct, within-chunk (oh&1)*64 + l15
    float* ybase = y + (size_t)b * COUT * YPLANE
                 + (size_t)((rp * 2 + ct) * YCHUNK) + (oh & 1) * 64 + l15;

#pragma unroll
    for (int mt = 0; mt < 4; ++mt) {
        float s1 = 0.f, s2 = 0.f;
#pragma unroll
        for (int r2 = 0; r2 < 4; ++r2) {
            int co = wm * 64 + mt * 16 + lhi * 4 + r2;
            float* yp = ybase + (size_t)co * YPLANE;
#pragma unroll
            for (int nt = 0; nt < 4; ++nt) {
                float v = acc[mt][nt][r2] + cbv[mt][r2];
                yp[nt * 16] = v;
                if (ct * 64 + nt * 16 + l15 < WOUT) { s1 += v; s2 += v * v; }
            }
        }
#pragma unroll
        for (int d = 1; d < 32; d <<= 1) {
            s1 += __shfl_xor(s1, d);
            s2 += __shfl_xor(s2, d);
        }
        if ((l & 31) == 0) {
            wred[wid][mt][l >> 5][0] = s1;
            wred[wid][mt][l >> 5][1] = s2;
        }
    }
    __syncthreads();

    if (tid < NG) {
        int g = tid;
        int gwm = g >> 3, mt = (g >> 1) & 3, half = g & 1;
        float t1 = 0.f, t2 = 0.f;
#pragma unroll
        for (int wrv = 0; wrv < 2; ++wrv) {
            t1 += wred[wrv * 2 + gwm][mt][half][0];
            t2 += wred[wrv * 2 + gwm][mt][half][1];
        }
        size_t pidx = (((size_t)b * NG + g) * NTILE + (rp * 2 + ct)) * 2;
        partials[pidx + 0] = t1;
        partials[pidx + 1] = t2;
    }
}

__global__ void stats_kernel(const float* __restrict__ partials,
                             float* __restrict__ stats)
{
    int t = blockIdx.x * blockDim.x + threadIdx.x;
    if (t >= NB * NG) return;
    float s1 = 0.f, s2 = 0.f;
    for (int j = 0; j < NTILE; ++j) {
        s1 += partials[((size_t)t * NTILE + j) * 2 + 0];
        s2 += partials[((size_t)t * NTILE + j) * 2 + 1];
    }
    const float N = 8.f * HOUT * WOUT;
    float mean = s1 / N;
    float var = s2 / N - mean * mean;
    stats[t * 2 + 0] = mean;
    stats[t * 2 + 1] = rsqrtf(var + EPS);
}

__global__ __launch_bounds__(256) void pool_kernel(
    const float* __restrict__ y, const float* __restrict__ stats,
    const float* __restrict__ gw, const float* __restrict__ gb,
    const float* __restrict__ sc, float* __restrict__ out)
{
    int idx = blockIdx.x * 256 + threadIdx.x;
    if (idx >= NB * COUT * HP * WP) return;
    int owp = idx % WP;
    int t = idx / WP;
    int ohp = t % HP; t /= HP;
    int c = t % COUT;
    int b = t / COUT;
    int g = c >> 3;

    float mean = stats[(b * NG + g) * 2 + 0];
    float rstd = stats[(b * NG + g) * 2 + 1];
    float ga = rstd * gw[c] * sc[c];
    float gbb = (gb[c] - mean * rstd * gw[c]) * sc[c];

    // tiled y: chunk = ohp*2 + (owp>>5); rows (0,1) of chunk; col = (2*owp)&63
    int ct = owp >> 5, col = (2 * owp) & 63;
    const float* yp = y + (size_t)(b * COUT + c) * YPLANE
                    + (ohp * 2 + ct) * YCHUNK + col;
    float2 r0 = *reinterpret_cast<const float2*>(yp);
    float2 r1 = *reinterpret_cast<const float2*>(yp + 64);
    float v0 = fmaf(r0.x, ga, gbb);
    float v1 = fmaf(r0.y, ga, gbb);
    float v2 = fmaf(r1.x, ga, gbb);
    float v3 = fmaf(r1.y, ga, gbb);
    float m = fmaxf(fmaxf(v0, v1), fmaxf(v2, v3));
    out[idx] = fminf(fmaxf(m, 0.f), 1.f);
}

extern "C" void kernel_launch(void* const* d_in, const int* in_sizes, int n_in,
                              void* d_out, int out_size, void* d_ws, size_t ws_size,
                              hipStream_t stream)
{
    const float* x  = (const float*)d_in[0];
    const float* cw = (const float*)d_in[1];
    const float* cbias = (const float*)d_in[2];
    const float* gw = (const float*)d_in[3];
    const float* gb = (const float*)d_in[4];
    const float* sc = (const float*)d_in[5];
    float* out = (float*)d_out;

    // ws: y 264,241,152 B + partials 1,032,192 + stats 4,096 + weights 294,912
    //   = 265,572,352 B = 253.3 MiB < 256 MiB
    const size_t YSZ = (size_t)NB * COUT * YPLANE;               // 66,060,288 f32
    float* y        = (float*)d_ws;
    float* partials = y + YSZ;                                   // 32*16*126*2 f32
    float* stats    = partials + (size_t)NB * NG * NTILE * 2;    // 1024 f32
    ushort* wh      = (ushort*)(stats + 1024);                   // 128*576 bf16
    ushort* wl      = wh + (size_t)COUT * KTOT;

    hipLaunchKernelGGL(wprep_kernel, dim3((COUT * KTOT + 255) / 256), dim3(256),
                       0, stream, cw, wh, wl);

    hipLaunchKernelGGL(conv_mfma_kernel, dim3(4032), dim3(256), 0, stream,
                       x, wh, wl, cbias, y, partials);

    hipLaunchKernelGGL(stats_kernel, dim3(2), dim3(256), 0, stream,
                       partials, stats);

    int total = NB * COUT * HP * WP;
    hipLaunchKernelGGL(pool_kernel, dim3((total + 255) / 256), dim3(256), 0, stream,
                       y, stats, gw, gb, sc, out);
}

// Round 7
// 507.447 us; speedup vs baseline: 1.5382x; 1.0141x over previous
//
#include <hip/hip_runtime.h>
#include <hip/hip_fp16.h>

#define CIN   64
#define COUT  128
#define HIN   128
#define WIN   128
#define HOUT  126
#define WOUT  126
#define HP    63
#define WP    63
#define NB    32
#define NG    16
#define EPS   1e-5f
#define KTOT  576            // 9 * 64, k = (kh*3+kw)*64 + ci

// LDS x-tile (f16): [4 rows][66 cols][cell = 32 ci f16 (64B) + 16B pad = 80B]
#define CELLB 80
#define NCOLT 66
#define ROWB  (NCOLT * CELLB)   // 5280
#define XBYTES (4 * ROWB)       // 21120
#define NTILE 126               // rp*2 + ct

// tiled y: [b][co][chunk(126)][row(2)][col(64)] ; chunk = 128 floats (512B)
#define YCHUNK 128
#define YPLANE (126 * YCHUNK)   // 16128 floats per (b,co)

typedef __attribute__((ext_vector_type(8))) _Float16 half8;
typedef __attribute__((ext_vector_type(4))) float f32x4;

// ---- weight prep: cw[co][ci][3][3] f32 -> wt[co][k] f16 hi/lo, k=(kh*3+kw)*64+ci
__global__ __launch_bounds__(256) void wprep_kernel(
    const float* __restrict__ cw, ushort* __restrict__ wh, ushort* __restrict__ wl)
{
    int idx = blockIdx.x * 256 + threadIdx.x;
    if (idx >= COUT * KTOT) return;
    int co = idx / KTOT, k = idx - co * KTOT;
    int khw = k >> 6, ci = k & 63;
    float v = cw[(co * CIN + ci) * 9 + khw];
    __half h = __float2half(v);
    __half l = __float2half(v - __half2float(h));
    wh[idx] = __half_as_ushort(h);
    wl[idx] = __half_as_ushort(l);
}

// ---- conv implicit GEMM: block = 2 out rows x 64 cols x 128 couts, 4 waves
__global__ __launch_bounds__(256, 4) void conv_mfma_kernel(
    const float* __restrict__ x, const ushort* __restrict__ wt_hi,
    const ushort* __restrict__ wt_lo, const float* __restrict__ cb,
    float* __restrict__ y, float* __restrict__ partials)
{
    __shared__ char xs[XBYTES];
    __shared__ float wred[4][4][2][2];

    const int tid = threadIdx.x;
    // XCD swizzle: 4032 blocks = 8 XCDs x 504; each XCD gets 4 whole images
    const int bid = blockIdx.x;
    const int w   = (bid & 7) * 504 + (bid >> 3);
    const int b   = w / 126;
    const int r   = w - b * 126;
    const int rp  = r >> 1;            // 0..62 row pair
    const int ct  = r & 1;             // col tile
    const int r0x = rp * 2;            // first x row needed

    const int l = tid & 63, wid = tid >> 6;
    const int wr = wid >> 1, wm = wid & 1;       // wr: row, wm: cout half
    const int l15 = l & 15, lhi = l >> 4;

    f32x4 acc[4][4];
#pragma unroll
    for (int mt = 0; mt < 4; ++mt)
#pragma unroll
        for (int nt = 0; nt < 4; ++nt)
            acc[mt][nt] = (f32x4){0.f, 0.f, 0.f, 0.f};

    const float* xb = x + (size_t)b * (CIN * HIN * WIN);
    const char* pbh = xs + wr * ROWB + l15 * CELLB + lhi * 16;

    for (int cip = 0; cip < 2; ++cip) {
        if (cip) __syncthreads();                // prev compute done
        // ---- stage 32-ci chunk as f16: tasks = cig(8) x row(4) x c4(17) = 544
        for (int t = 0; t < 3; ++t) {
            int gid = t * 256 + tid;
            if (gid < 544) {
                int c4  = gid % 17;
                int rr  = (gid / 17) & 3;
                int cig = gid / 68;
                int row = r0x + rr;               // always < HIN
                bool colok = (ct == 0) | (c4 < 16);   // avoid OOB float4 at gcol=128
                f32x4 f[4];
                const float* xp = xb + (size_t)(cip * 32 + cig * 4) * (HIN * WIN)
                                + row * WIN + ct * 64 + c4 * 4;
#pragma unroll
                for (int q = 0; q < 4; ++q) {
                    if (colok)
                        f[q] = *(const f32x4*)(xp + q * (HIN * WIN));
                    else
                        f[q] = (f32x4){0.f, 0.f, 0.f, 0.f};
                }
#pragma unroll
                for (int j = 0; j < 4; ++j) {
                    int lc = c4 * 4 + j;
                    if (lc < NCOLT) {
                        // 4 consecutive ci (planes q=0..3) for column lc
                        ushort h0 = __half_as_ushort(__float2half(f[0][j]));
                        ushort h1 = __half_as_ushort(__float2half(f[1][j]));
                        ushort h2 = __half_as_ushort(__float2half(f[2][j]));
                        ushort h3 = __half_as_ushort(__float2half(f[3][j]));
                        uint2 hp;
                        hp.x = (unsigned)h0 | ((unsigned)h1 << 16);
                        hp.y = (unsigned)h2 | ((unsigned)h3 << 16);
                        *(uint2*)(xs + (rr * NCOLT + lc) * CELLB + cig * 8) = hp;
                    }
                }
            }
        }
        __syncthreads();

        // ---- compute this ci-chunk: 2 f16 MFMAs (w-hi, w-lo) per (mt,nt,khw)
        const ushort* wbh = wt_hi + (size_t)(wm * 64 + l15) * KTOT + cip * 32 + lhi * 8;
        const ushort* wbl = wt_lo + (size_t)(wm * 64 + l15) * KTOT + cip * 32 + lhi * 8;
#pragma unroll
        for (int kh = 0; kh < 3; ++kh) {
#pragma unroll
            for (int kw = 0; kw < 3; ++kw) {
                const int khw = kh * 3 + kw;
                half8 bh[4];
#pragma unroll
                for (int nt = 0; nt < 4; ++nt)
                    bh[nt] = *(const half8*)(pbh + kh * ROWB + (nt * 16 + kw) * CELLB);
#pragma unroll
                for (int mt = 0; mt < 4; ++mt) {
                    half8 ah = *(const half8*)(wbh + mt * 16 * KTOT + khw * 64);
                    half8 al = *(const half8*)(wbl + mt * 16 * KTOT + khw * 64);
#pragma unroll
                    for (int nt = 0; nt < 4; ++nt) {
                        acc[mt][nt] = __builtin_amdgcn_mfma_f32_16x16x32_f16(
                            ah, bh[nt], acc[mt][nt], 0, 0, 0);
                        acc[mt][nt] = __builtin_amdgcn_mfma_f32_16x16x32_f16(
                            al, bh[nt], acc[mt][nt], 0, 0, 0);
                    }
                }
            }
        }
    }

    // ---- epilogue: bias, store y (all rows valid), group partials
    const int oh = r0x + wr;
    float cbv[4][4];
#pragma unroll
    for (int mt = 0; mt < 4; ++mt)
#pragma unroll
        for (int r2 = 0; r2 < 4; ++r2)
            cbv[mt][r2] = cb[wm * 64 + mt * 16 + lhi * 4 + r2];

    float* ybase = y + (size_t)b * COUT * YPLANE
                 + (size_t)((rp * 2 + ct) * YCHUNK) + (oh & 1) * 64 + l15;

#pragma unroll
    for (int mt = 0; mt < 4; ++mt) {
        float s1 = 0.f, s2 = 0.f;
#pragma unroll
        for (int r2 = 0; r2 < 4; ++r2) {
            int co = wm * 64 + mt * 16 + lhi * 4 + r2;
            float* yp = ybase + (size_t)co * YPLANE;
#pragma unroll
            for (int nt = 0; nt < 4; ++nt) {
                float v = acc[mt][nt][r2] + cbv[mt][r2];
                yp[nt * 16] = v;
                if (ct * 64 + nt * 16 + l15 < WOUT) { s1 += v; s2 += v * v; }
            }
        }
#pragma unroll
        for (int d = 1; d < 32; d <<= 1) {
            s1 += __shfl_xor(s1, d);
            s2 += __shfl_xor(s2, d);
        }
        if ((l & 31) == 0) {
            wred[wid][mt][l >> 5][0] = s1;
            wred[wid][mt][l >> 5][1] = s2;
        }
    }
    __syncthreads();

    if (tid < NG) {
        int g = tid;
        int gwm = g >> 3, mt = (g >> 1) & 3, half = g & 1;
        float t1 = 0.f, t2 = 0.f;
#pragma unroll
        for (int wrv = 0; wrv < 2; ++wrv) {
            t1 += wred[wrv * 2 + gwm][mt][half][0];
            t2 += wred[wrv * 2 + gwm][mt][half][1];
        }
        size_t pidx = (((size_t)b * NG + g) * NTILE + (rp * 2 + ct)) * 2;
        partials[pidx + 0] = t1;
        partials[pidx + 1] = t2;
    }
}

__global__ void stats_kernel(const float* __restrict__ partials,
                             float* __restrict__ stats)
{
    int t = blockIdx.x * blockDim.x + threadIdx.x;
    if (t >= NB * NG) return;
    float s1 = 0.f, s2 = 0.f;
    for (int j = 0; j < NTILE; ++j) {
        s1 += partials[((size_t)t * NTILE + j) * 2 + 0];
        s2 += partials[((size_t)t * NTILE + j) * 2 + 1];
    }
    const float N = 8.f * HOUT * WOUT;
    float mean = s1 / N;
    float var = s2 / N - mean * mean;
    stats[t * 2 + 0] = mean;
    stats[t * 2 + 1] = rsqrtf(var + EPS);
}

__global__ __launch_bounds__(256) void pool_kernel(
    const float* __restrict__ y, const float* __restrict__ stats,
    const float* __restrict__ gw, const float* __restrict__ gb,
    const float* __restrict__ sc, float* __restrict__ out)
{
    int idx = blockIdx.x * 256 + threadIdx.x;
    if (idx >= NB * COUT * HP * WP) return;
    int owp = idx % WP;
    int t = idx / WP;
    int ohp = t % HP; t /= HP;
    int c = t % COUT;
    int b = t / COUT;
    int g = c >> 3;

    float mean = stats[(b * NG + g) * 2 + 0];
    float rstd = stats[(b * NG + g) * 2 + 1];
    float ga = rstd * gw[c] * sc[c];
    float gbb = (gb[c] - mean * rstd * gw[c]) * sc[c];

    // tiled y: chunk = ohp*2 + (owp>>5); rows (0,1) of chunk; col = (2*owp)&63
    int ct = owp >> 5, col = (2 * owp) & 63;
    const float* yp = y + (size_t)(b * COUT + c) * YPLANE
                    + (ohp * 2 + ct) * YCHUNK + col;
    float2 r0 = *reinterpret_cast<const float2*>(yp);
    float2 r1 = *reinterpret_cast<const float2*>(yp + 64);
    float v0 = fmaf(r0.x, ga, gbb);
    float v1 = fmaf(r0.y, ga, gbb);
    float v2 = fmaf(r1.x, ga, gbb);
    float v3 = fmaf(r1.y, ga, gbb);
    float m = fmaxf(fmaxf(v0, v1), fmaxf(v2, v3));
    out[idx] = fminf(fmaxf(m, 0.f), 1.f);
}

extern "C" void kernel_launch(void* const* d_in, const int* in_sizes, int n_in,
                              void* d_out, int out_size, void* d_ws, size_t ws_size,
                              hipStream_t stream)
{
    const float* x  = (const float*)d_in[0];
    const float* cw = (const float*)d_in[1];
    const float* cbias = (const float*)d_in[2];
    const float* gw = (const float*)d_in[3];
    const float* gb = (const float*)d_in[4];
    const float* sc = (const float*)d_in[5];
    float* out = (float*)d_out;

    // ws: y 264,241,152 B + partials 1,032,192 + stats 4,096 + weights 294,912
    //   = 265,572,352 B = 253.3 MiB < 256 MiB
    const size_t YSZ = (size_t)NB * COUT * YPLANE;               // 66,060,288 f32
    float* y        = (float*)d_ws;
    float* partials = y + YSZ;                                   // 32*16*126*2 f32
    float* stats    = partials + (size_t)NB * NG * NTILE * 2;    // 1024 f32
    ushort* wh      = (ushort*)(stats + 1024);                   // 128*576 f16
    ushort* wl      = wh + (size_t)COUT * KTOT;

    hipLaunchKernelGGL(wprep_kernel, dim3((COUT * KTOT + 255) / 256), dim3(256),
                       0, stream, cw, wh, wl);

    hipLaunchKernelGGL(conv_mfma_kernel, dim3(4032), dim3(256), 0, stream,
                       x, wh, wl, cbias, y, partials);

    hipLaunchKernelGGL(stats_kernel, dim3(2), dim3(256), 0, stream,
                       partials, stats);

    int total = NB * COUT * HP * WP;
    hipLaunchKernelGGL(pool_kernel, dim3((total + 255) / 256), dim3(256), 0, stream,
                       y, stats, gw, gb, sc, out);
}

// Round 8
// 318.989 us; speedup vs baseline: 2.4470x; 1.5908x over previous
//
#include <hip/hip_runtime.h>
#include <hip/hip_fp16.h>

#define CIN   64
#define COUT  128
#define HIN   128
#define WIN   128
#define HOUT  126
#define WOUT  126
#define HP    63
#define WP    63
#define NB    32
#define NG    16
#define EPS   1e-5f
#define KTOT  576            // 9 * 64, k = (kh*3+kw)*64 + ci

// LDS x-tile (f16): [4 rows][66 cols][cell = 64 ci f16 (128B) + 16B pad = 144B]
#define CELLB 144
#define NCOLT 66
#define ROWB  (NCOLT * CELLB)   // 9504
#define XBYTES (4 * ROWB)       // 38016
#define NTILE 126               // rp*2 + ct

// tiled y: [b][co][chunk(126)][row(2)][col(64)] ; chunk = 128 floats (512B)
#define YCHUNK 128
#define YPLANE (126 * YCHUNK)   // 16128 floats per (b,co)

typedef __attribute__((ext_vector_type(8))) _Float16 half8;
typedef __attribute__((ext_vector_type(4))) float f32x4;

// ---- weight prep: cw[co][ci][3][3] f32 -> wt[co][k] f16 hi/lo, k=(kh*3+kw)*64+ci
__global__ __launch_bounds__(256) void wprep_kernel(
    const float* __restrict__ cw, ushort* __restrict__ wh, ushort* __restrict__ wl)
{
    int idx = blockIdx.x * 256 + threadIdx.x;
    if (idx >= COUT * KTOT) return;
    int co = idx / KTOT, k = idx - co * KTOT;
    int khw = k >> 6, ci = k & 63;
    float v = cw[(co * CIN + ci) * 9 + khw];
    __half h = __float2half(v);
    __half l = __float2half(v - __half2float(h));
    wh[idx] = __half_as_ushort(h);
    wl[idx] = __half_as_ushort(l);
}

// ---- conv implicit GEMM: block = 2 out rows x 64 cols x 128 couts, 4 waves
// wave = 32 couts (2 mt) x 128 spatial (8 nt)  [weight-load-light partition]
__global__ __launch_bounds__(256, 3) void conv_mfma_kernel(
    const float* __restrict__ x, const ushort* __restrict__ wt_hi,
    const ushort* __restrict__ wt_lo, const float* __restrict__ cb,
    float* __restrict__ y, float* __restrict__ partials)
{
    __shared__ char xs[XBYTES];
    __shared__ float wred[4][2][4][2];

    const int tid = threadIdx.x;
    // XCD swizzle: 4032 blocks = 8 XCDs x 504; each XCD gets 4 whole images
    const int bid = blockIdx.x;
    const int w   = (bid & 7) * 504 + (bid >> 3);
    const int b   = w / 126;
    const int r   = w - b * 126;
    const int rp  = r >> 1;            // 0..62 row pair
    const int ct  = r & 1;             // col tile
    const int r0x = rp * 2;            // first x row needed (<=124)

    const int l = tid & 63, wid = tid >> 6;   // wid: cout quarter (32 couts)
    const int l15 = l & 15, lhi = l >> 4;

    f32x4 acc[2][8];
#pragma unroll
    for (int mt = 0; mt < 2; ++mt)
#pragma unroll
        for (int nt = 0; nt < 8; ++nt)
            acc[mt][nt] = (f32x4){0.f, 0.f, 0.f, 0.f};

    const float* xb = x + (size_t)b * (CIN * HIN * WIN);

    // ---- stage full 64-ci x-tile as f16: tasks = cig(16) x row(4) x c4(17) = 1088
    for (int t = 0; t < 5; ++t) {
        int gid = t * 256 + tid;
        if (gid < 1088) {
            int c4  = gid % 17;
            int rr  = (gid / 17) & 3;
            int cig = gid / 68;                  // 0..15 (4-ci groups)
            int row = r0x + rr;                  // always < HIN
            bool colok = (ct == 0) | (c4 < 16);  // avoid OOB float4 at gcol=128
            f32x4 f[4];
            const float* xp = xb + (size_t)(cig * 4) * (HIN * WIN)
                            + row * WIN + ct * 64 + c4 * 4;
#pragma unroll
            for (int q = 0; q < 4; ++q) {
                if (colok)
                    f[q] = *(const f32x4*)(xp + q * (HIN * WIN));
                else
                    f[q] = (f32x4){0.f, 0.f, 0.f, 0.f};
            }
#pragma unroll
            for (int j = 0; j < 4; ++j) {
                int lc = c4 * 4 + j;
                if (lc < NCOLT) {
                    ushort h0 = __half_as_ushort(__float2half(f[0][j]));
                    ushort h1 = __half_as_ushort(__float2half(f[1][j]));
                    ushort h2 = __half_as_ushort(__float2half(f[2][j]));
                    ushort h3 = __half_as_ushort(__float2half(f[3][j]));
                    uint2 hp;
                    hp.x = (unsigned)h0 | ((unsigned)h1 << 16);
                    hp.y = (unsigned)h2 | ((unsigned)h3 << 16);
                    *(uint2*)(xs + (rr * NCOLT + lc) * CELLB + cig * 8) = hp;
                }
            }
        }
    }
    __syncthreads();

    // ---- K loop: cip(2) x kh(3) x kw(3); weights batched 12/kh into registers
    const ushort* wbh = wt_hi + (size_t)(wid * 32 + l15) * KTOT + lhi * 8;
    const ushort* wbl = wt_lo + (size_t)(wid * 32 + l15) * KTOT + lhi * 8;
    const char* pb = xs + l15 * CELLB + lhi * 16;

#pragma unroll
    for (int cip = 0; cip < 2; ++cip) {
#pragma unroll
        for (int kh = 0; kh < 3; ++kh) {
            half8 wfh[2][3], wfl[2][3];
#pragma unroll
            for (int mt = 0; mt < 2; ++mt)
#pragma unroll
                for (int kw = 0; kw < 3; ++kw) {
                    int off = mt * 16 * KTOT + (kh * 3 + kw) * 64 + cip * 32;
                    wfh[mt][kw] = *(const half8*)(wbh + off);
                    wfl[mt][kw] = *(const half8*)(wbl + off);
                }
#pragma unroll
            for (int kw = 0; kw < 3; ++kw) {
                half8 bh[8];
#pragma unroll
                for (int nt = 0; nt < 8; ++nt)
                    bh[nt] = *(const half8*)(pb + ((nt >> 2) + kh) * ROWB
                            + ((nt & 3) * 16 + kw) * CELLB + cip * 64);
#pragma unroll
                for (int mt = 0; mt < 2; ++mt)
#pragma unroll
                    for (int nt = 0; nt < 8; ++nt) {
                        acc[mt][nt] = __builtin_amdgcn_mfma_f32_16x16x32_f16(
                            wfh[mt][kw], bh[nt], acc[mt][nt], 0, 0, 0);
                        acc[mt][nt] = __builtin_amdgcn_mfma_f32_16x16x32_f16(
                            wfl[mt][kw], bh[nt], acc[mt][nt], 0, 0, 0);
                    }
            }
        }
    }

    // ---- epilogue: bias, store y (all rows valid), group partials
    float cbv[2][4];
#pragma unroll
    for (int mt = 0; mt < 2; ++mt)
#pragma unroll
        for (int r2 = 0; r2 < 4; ++r2)
            cbv[mt][r2] = cb[wid * 32 + mt * 16 + lhi * 4 + r2];

    float* ybase = y + (size_t)b * COUT * YPLANE
                 + (size_t)((rp * 2 + ct) * YCHUNK) + l15;

#pragma unroll
    for (int mt = 0; mt < 2; ++mt) {
        float s1 = 0.f, s2 = 0.f;
#pragma unroll
        for (int r2 = 0; r2 < 4; ++r2) {
            int co = wid * 32 + mt * 16 + lhi * 4 + r2;
            float* yp = ybase + (size_t)co * YPLANE;
#pragma unroll
            for (int nt = 0; nt < 8; ++nt) {
                float v = acc[mt][nt][r2] + cbv[mt][r2];
                yp[(nt >> 2) * 64 + (nt & 3) * 16] = v;
                if (ct * 64 + (nt & 3) * 16 + l15 < WOUT) { s1 += v; s2 += v * v; }
            }
        }
        // reduce over the 16 spatial lanes (same lhi => same couts)
#pragma unroll
        for (int d = 1; d < 16; d <<= 1) {
            s1 += __shfl_xor(s1, d);
            s2 += __shfl_xor(s2, d);
        }
        if (l15 == 0) {
            wred[wid][mt][lhi][0] = s1;
            wred[wid][mt][lhi][1] = s2;
        }
    }
    __syncthreads();

    if (tid < NG) {
        int g = tid;                     // couts [g*8, g*8+8)
        int gw = g >> 2, mt = (g >> 1) & 1, h = g & 1;
        float t1 = wred[gw][mt][h * 2][0] + wred[gw][mt][h * 2 + 1][0];
        float t2 = wred[gw][mt][h * 2][1] + wred[gw][mt][h * 2 + 1][1];
        size_t pidx = (((size_t)b * NG + g) * NTILE + (rp * 2 + ct)) * 2;
        partials[pidx + 0] = t1;
        partials[pidx + 1] = t2;
    }
}

__global__ void stats_kernel(const float* __restrict__ partials,
                             float* __restrict__ stats)
{
    int t = blockIdx.x * blockDim.x + threadIdx.x;
    if (t >= NB * NG) return;
    float s1 = 0.f, s2 = 0.f;
    for (int j = 0; j < NTILE; ++j) {
        s1 += partials[((size_t)t * NTILE + j) * 2 + 0];
        s2 += partials[((size_t)t * NTILE + j) * 2 + 1];
    }
    const float N = 8.f * HOUT * WOUT;
    float mean = s1 / N;
    float var = s2 / N - mean * mean;
    stats[t * 2 + 0] = mean;
    stats[t * 2 + 1] = rsqrtf(var + EPS);
}

__global__ __launch_bounds__(256) void pool_kernel(
    const float* __restrict__ y, const float* __restrict__ stats,
    const float* __restrict__ gw, const float* __restrict__ gb,
    const float* __restrict__ sc, float* __restrict__ out)
{
    int idx = blockIdx.x * 256 + threadIdx.x;
    if (idx >= NB * COUT * HP * WP) return;
    int owp = idx % WP;
    int t = idx / WP;
    int ohp = t % HP; t /= HP;
    int c = t % COUT;
    int b = t / COUT;
    int g = c >> 3;

    float mean = stats[(b * NG + g) * 2 + 0];
    float rstd = stats[(b * NG + g) * 2 + 1];
    float ga = rstd * gw[c] * sc[c];
    float gbb = (gb[c] - mean * rstd * gw[c]) * sc[c];

    // tiled y: chunk = ohp*2 + (owp>>5); rows (0,1) of chunk; col = (2*owp)&63
    int ct = owp >> 5, col = (2 * owp) & 63;
    const float* yp = y + (size_t)(b * COUT + c) * YPLANE
                    + (ohp * 2 + ct) * YCHUNK + col;
    float2 r0 = *reinterpret_cast<const float2*>(yp);
    float2 r1 = *reinterpret_cast<const float2*>(yp + 64);
    float v0 = fmaf(r0.x, ga, gbb);
    float v1 = fmaf(r0.y, ga, gbb);
    float v2 = fmaf(r1.x, ga, gbb);
    float v3 = fmaf(r1.y, ga, gbb);
    float m = fmaxf(fmaxf(v0, v1), fmaxf(v2, v3));
    out[idx] = fminf(fmaxf(m, 0.f), 1.f);
}

extern "C" void kernel_launch(void* const* d_in, const int* in_sizes, int n_in,
                              void* d_out, int out_size, void* d_ws, size_t ws_size,
                              hipStream_t stream)
{
    const float* x  = (const float*)d_in[0];
    const float* cw = (const float*)d_in[1];
    const float* cbias = (const float*)d_in[2];
    const float* gw = (const float*)d_in[3];
    const float* gb = (const float*)d_in[4];
    const float* sc = (const float*)d_in[5];
    float* out = (float*)d_out;

    // ws: y 264,241,152 B + partials 1,032,192 + stats 4,096 + weights 294,912
    //   = 265,572,352 B = 253.3 MiB < 256 MiB
    const size_t YSZ = (size_t)NB * COUT * YPLANE;               // 66,060,288 f32
    float* y        = (float*)d_ws;
    float* partials = y + YSZ;                                   // 32*16*126*2 f32
    float* stats    = partials + (size_t)NB * NG * NTILE * 2;    // 1024 f32
    ushort* wh      = (ushort*)(stats + 1024);                   // 128*576 f16
    ushort* wl      = wh + (size_t)COUT * KTOT;

    hipLaunchKernelGGL(wprep_kernel, dim3((COUT * KTOT + 255) / 256), dim3(256),
                       0, stream, cw, wh, wl);

    hipLaunchKernelGGL(conv_mfma_kernel, dim3(4032), dim3(256), 0, stream,
                       x, wh, wl, cbias, y, partials);

    hipLaunchKernelGGL(stats_kernel, dim3(2), dim3(256), 0, stream,
                       partials, stats);

    int total = NB * COUT * HP * WP;
    hipLaunchKernelGGL(pool_kernel, dim3((total + 255) / 256), dim3(256), 0, stream,
                       y, stats, gw, gb, sc, out);
}